// Round 1
// baseline (3015.791 us; speedup 1.0000x reference)
//
#include <hip/hip_runtime.h>
#include <hip/hip_bf16.h>
#include <math.h>

#define D_MODEL 1024
#define C_DIM   128
#define BATCH   4
#define SEQ     2048

// ---------------------------------------------------------------------------
// Kernel 1: q = x@A (masked), k = x@Bmat^T   -> qm[b,s,c], kk[b,s,c]
// one block per (b,s) row; 256 threads: 128 do q, 128 do k
// ---------------------------------------------------------------------------
__launch_bounds__(256)
__global__ void qk_kernel(const float* __restrict__ x,
                          const float* __restrict__ A,
                          const float* __restrict__ Bm,
                          const float* __restrict__ mask,
                          float* __restrict__ qm,
                          float* __restrict__ kk) {
    __shared__ float xrow[D_MODEL];
    const int bs  = blockIdx.x;                 // 0 .. BATCH*SEQ-1
    const int tid = threadIdx.x;

    // stage x row (1024 floats) via float4
    reinterpret_cast<float4*>(xrow)[tid] =
        reinterpret_cast<const float4*>(x + (size_t)bs * D_MODEL)[tid];
    __syncthreads();

    if (tid < C_DIM) {
        const int c = tid;
        float acc = 0.f;
        // A[d, c]: at fixed d, threads read consecutive c -> coalesced
        #pragma unroll 8
        for (int d = 0; d < D_MODEL; ++d) acc += xrow[d] * A[d * C_DIM + c];
        const size_t o = (size_t)bs * C_DIM + c;
        qm[o] = acc * mask[o];
    } else {
        const int c = tid - C_DIM;
        const float* br = Bm + (size_t)c * D_MODEL;  // Bmat row c (contiguous)
        float acc = 0.f;
        #pragma unroll 8
        for (int d = 0; d < D_MODEL; ++d) acc += xrow[d] * br[d];
        kk[(size_t)bs * C_DIM + c] = acc;
    }
}

// ---------------------------------------------------------------------------
// Kernel 2: per query row: scores (causal) -> softmax -> z = patt @ x
// one block (256 threads) per (b, q)
// ---------------------------------------------------------------------------
__launch_bounds__(256)
__global__ void attn_kernel(const float* __restrict__ x,
                            const float* __restrict__ qm,
                            const float* __restrict__ kk,
                            float* __restrict__ z) {
    __shared__ float sc[SEQ];      // scores / probs
    __shared__ float qs[C_DIM];    // this row's masked query
    __shared__ float red[8];       // per-wave partials (4 waves)

    const int q   = blockIdx.x & (SEQ - 1);
    const int b   = blockIdx.x >> 11;           // SEQ = 2048 = 1<<11
    const int tid = threadIdx.x;
    const int nk  = q + 1;                      // causal: keys 0..q

    if (tid < C_DIM) qs[tid] = qm[((size_t)b * SEQ + q) * C_DIM + tid];
    __syncthreads();

    // scores
    float lmax = -INFINITY;
    for (int k = tid; k < nk; k += 256) {
        const float* kr = kk + ((size_t)b * SEQ + k) * C_DIM;
        float s = 0.f;
        #pragma unroll 16
        for (int c = 0; c < C_DIM; ++c) s += qs[c] * kr[c];
        s *= (1.0f / (float)D_MODEL);
        sc[k] = s;
        lmax = fmaxf(lmax, s);
    }
    // block max (wave64 shuffle then LDS)
    for (int off = 32; off > 0; off >>= 1) lmax = fmaxf(lmax, __shfl_xor(lmax, off));
    const int wave = tid >> 6;
    if ((tid & 63) == 0) red[wave] = lmax;
    __syncthreads();
    const float m = fmaxf(fmaxf(red[0], red[1]), fmaxf(red[2], red[3]));

    // exp + sum
    float lsum = 0.f;
    for (int k = tid; k < nk; k += 256) {
        float e = __expf(sc[k] - m);
        sc[k] = e;
        lsum += e;
    }
    for (int off = 32; off > 0; off >>= 1) lsum += __shfl_xor(lsum, off);
    if ((tid & 63) == 0) red[4 + wave] = lsum;
    __syncthreads();
    const float inv = 1.0f / (red[4] + red[5] + red[6] + red[7]);

    // z[q, :] = sum_k patt[k] * x[b, k, :]; thread owns float4 at col 4*tid
    const float4* xb = reinterpret_cast<const float4*>(x + (size_t)b * SEQ * D_MODEL);
    float4 acc = make_float4(0.f, 0.f, 0.f, 0.f);
    for (int k = 0; k < nk; ++k) {
        const float p = sc[k];
        const float4 xv = xb[(size_t)k * (D_MODEL / 4) + tid];
        acc.x += p * xv.x; acc.y += p * xv.y; acc.z += p * xv.z; acc.w += p * xv.w;
    }
    acc.x *= inv; acc.y *= inv; acc.z *= inv; acc.w *= inv;
    reinterpret_cast<float4*>(z + ((size_t)b * SEQ + q) * D_MODEL)[tid] = acc;
}

// ---------------------------------------------------------------------------
// Kernel 3: out = z @ ov   (M=8192, K=1024, N=1024) fp32 tiled GEMM
// 64x64 tile, BK=16, 256 threads, 4x4 micro-tile per thread
// ---------------------------------------------------------------------------
__launch_bounds__(256)
__global__ void gemm_kernel(const float* __restrict__ z,
                            const float* __restrict__ ov,
                            float* __restrict__ out) {
    __shared__ float zt[64][17];   // +1 pad
    __shared__ float ot[16][64];

    const int tid = threadIdx.x;
    const int rb  = blockIdx.x * 64;   // row base (M)
    const int cb  = blockIdx.y * 64;   // col base (N)
    const int ty  = tid >> 4;          // 0..15
    const int tx  = tid & 15;          // 0..15

    float acc[4][4];
    #pragma unroll
    for (int i = 0; i < 4; ++i)
        #pragma unroll
        for (int j = 0; j < 4; ++j) acc[i][j] = 0.f;

    for (int kt = 0; kt < D_MODEL / 16; ++kt) {
        // load z tile 64x16
        #pragma unroll
        for (int l = tid; l < 64 * 16; l += 256) {
            const int r = l >> 4, c = l & 15;
            zt[r][c] = z[(size_t)(rb + r) * D_MODEL + kt * 16 + c];
        }
        // load ov tile 16x64
        #pragma unroll
        for (int l = tid; l < 16 * 64; l += 256) {
            const int r = l >> 6, c = l & 63;
            ot[r][c] = ov[(size_t)(kt * 16 + r) * D_MODEL + cb + c];
        }
        __syncthreads();

        #pragma unroll
        for (int kk2 = 0; kk2 < 16; ++kk2) {
            float zv[4], ovv[4];
            #pragma unroll
            for (int i = 0; i < 4; ++i) zv[i]  = zt[ty * 4 + i][kk2];
            #pragma unroll
            for (int j = 0; j < 4; ++j) ovv[j] = ot[kk2][tx * 4 + j];
            #pragma unroll
            for (int i = 0; i < 4; ++i)
                #pragma unroll
                for (int j = 0; j < 4; ++j) acc[i][j] += zv[i] * ovv[j];
        }
        __syncthreads();
    }

    #pragma unroll
    for (int i = 0; i < 4; ++i) {
        float4 v = make_float4(acc[i][0], acc[i][1], acc[i][2], acc[i][3]);
        *reinterpret_cast<float4*>(out + (size_t)(rb + ty * 4 + i) * D_MODEL + cb + tx * 4) = v;
    }
}

// ---------------------------------------------------------------------------
extern "C" void kernel_launch(void* const* d_in, const int* in_sizes, int n_in,
                              void* d_out, int out_size, void* d_ws, size_t ws_size,
                              hipStream_t stream) {
    const float* x    = (const float*)d_in[0];
    const float* A    = (const float*)d_in[1];
    const float* Bm   = (const float*)d_in[2];
    const float* ov   = (const float*)d_in[3];
    const float* mask = (const float*)d_in[4];
    float* out = (float*)d_out;

    // workspace layout (floats): qm [B*S*C] | kk [B*S*C] | z [B*S*D]
    float* qm = (float*)d_ws;
    float* kk = qm + (size_t)BATCH * SEQ * C_DIM;
    float* z  = kk + (size_t)BATCH * SEQ * C_DIM;
    // total = 2*4MB + 32MB = 40MB, assumed <= ws_size

    qk_kernel<<<BATCH * SEQ, 256, 0, stream>>>(x, A, Bm, mask, qm, kk);
    attn_kernel<<<BATCH * SEQ, 256, 0, stream>>>(x, qm, kk, z);
    dim3 g3((BATCH * SEQ) / 64, D_MODEL / 64);
    gemm_kernel<<<g3, 256, 0, stream>>>(z, ov, out);
}

// Round 2
// 162.092 us; speedup vs baseline: 18.6054x; 18.6054x over previous
//
#include <hip/hip_runtime.h>
#include <hip/hip_bf16.h>
#include <math.h>

#define D_MODEL 1024
#define C_DIM   128
#define BATCH   4
#define SEQ     2048
#define BS_ROWS (BATCH*SEQ)

typedef float  f32x4 __attribute__((ext_vector_type(4)));
typedef short  s16x8 __attribute__((ext_vector_type(8)));
typedef unsigned short u16;
typedef unsigned short u16x4 __attribute__((ext_vector_type(4)));

__device__ inline u16 f2bf(float f){
    unsigned u = __builtin_bit_cast(unsigned, f);
    u += 0x7FFF + ((u >> 16) & 1);          // round-to-nearest-even
    return (u16)(u >> 16);
}
__device__ inline float bf2f(u16 h){
    unsigned u = ((unsigned)h) << 16;
    return __builtin_bit_cast(float, u);
}

// async global->LDS, 16B per lane; LDS dest = wave-uniform base + lane*16
__device__ inline void gl_lds16(const u16* g, u16* l){
    __builtin_amdgcn_global_load_lds(
        (const __attribute__((address_space(1))) void*)g,
        (__attribute__((address_space(3))) void*)l,
        16, 0, 0);
}

// ---------------------------------------------------------------------------
// Generic bf16 MFMA GEMM:  C[M,N] = scale * A[M,K] @ BT[N,K]^T
// A row-major (lda), BT row-major N-major (ldb). 128x128 tile, BK=64,
// 4 waves each computing a 64x64 quadrant via 4x4 frags of 16x16x32 MFMA.
// OUT_BF16: write bf16 else fp32. MASK: multiply fp32 mask (same layout as C).
// CSKIP: skip tiles with nt>mt (causal scores). CK: causal K-extent (mt+1)*128.
// ---------------------------------------------------------------------------
template<int OUT_BF16, int MASK, int CSKIP, int CK>
__launch_bounds__(256)
__global__ void gemm_bt(const u16* __restrict__ Ag, const u16* __restrict__ Bg,
                        void* __restrict__ Cg, const float* __restrict__ maskp,
                        int M, int N, int K, int lda, int ldb, int ldc,
                        long sA, long sB, long sC, float scale)
{
    __shared__ u16 As[128*64];
    __shared__ u16 Bs[128*64];
    const int mt = blockIdx.x, nt = blockIdx.y;
    if (CSKIP && nt > mt) return;
    const u16* Aa = Ag + (long)blockIdx.z * sA;
    const u16* Bb = Bg + (long)blockIdx.z * sB;
    const int tid = threadIdx.x, lane = tid & 63, wave = tid >> 6;
    const int wr = wave >> 1, wc = wave & 1;
    const int mbase = mt * 128, nbase = nt * 128;
    int Keff = K;
    if (CK) { int ke = (mt + 1) * 128; Keff = ke < K ? ke : K; }
    const int nkt = Keff >> 6;

    f32x4 acc[4][4];
    #pragma unroll
    for (int m = 0; m < 4; ++m)
        #pragma unroll
        for (int n = 0; n < 4; ++n) acc[m][n] = (f32x4){0.f,0.f,0.f,0.f};

    // staging lane geometry: chunk = 8 rows x 64 cols (1KB); lane covers 16B
    const int sr  = lane >> 3;                 // row within chunk (0..7)
    const int sc8 = (lane & 7) ^ sr;           // XOR-swizzled 8-elem col slot

    for (int kt = 0; kt < nkt; ++kt) {
        const int k0 = kt * 64;
        #pragma unroll
        for (int i = 0; i < 4; ++i) {
            const int chunk = wave * 4 + i;    // 0..15
            const int row = chunk * 8 + sr;
            gl_lds16(Aa + (size_t)(mbase + row) * lda + k0 + sc8 * 8, &As[chunk * 512]);
            gl_lds16(Bb + (size_t)(nbase + row) * ldb + k0 + sc8 * 8, &Bs[chunk * 512]);
        }
        asm volatile("s_waitcnt vmcnt(0)" ::: "memory");
        __syncthreads();

        #pragma unroll
        for (int ks = 0; ks < 2; ++ks) {
            s16x8 af[4], bfr[4];
            const int k8 = ks * 4 + (lane >> 4);
            #pragma unroll
            for (int m = 0; m < 4; ++m) {
                const int row = wr * 64 + m * 16 + (lane & 15);
                af[m] = *(const s16x8*)&As[row * 64 + ((k8 ^ (row & 7)) << 3)];
            }
            #pragma unroll
            for (int n = 0; n < 4; ++n) {
                const int row = wc * 64 + n * 16 + (lane & 15);
                bfr[n] = *(const s16x8*)&Bs[row * 64 + ((k8 ^ (row & 7)) << 3)];
            }
            #pragma unroll
            for (int m = 0; m < 4; ++m)
                #pragma unroll
                for (int n = 0; n < 4; ++n)
                    acc[m][n] = __builtin_amdgcn_mfma_f32_16x16x32_bf16(af[m], bfr[n], acc[m][n], 0, 0, 0);
        }
        __syncthreads();
    }

    // epilogue: C/D layout col=lane&15, row=(lane>>4)*4+r (m89-verified)
    const int lr = (lane >> 4) * 4, lc = lane & 15;
    #pragma unroll
    for (int m = 0; m < 4; ++m) {
        #pragma unroll
        for (int n = 0; n < 4; ++n) {
            const int gr = mbase + wr * 64 + m * 16 + lr;
            const int gc = nbase + wc * 64 + n * 16 + lc;
            #pragma unroll
            for (int r = 0; r < 4; ++r) {
                float f = acc[m][n][r] * scale;
                const size_t off = (size_t)(gr + r) * ldc + gc;
                if (MASK) f *= maskp[(long)blockIdx.z * sC + off];
                if (OUT_BF16) ((u16*)Cg + (long)blockIdx.z * sC)[off] = f2bf(f);
                else          ((float*)Cg + (long)blockIdx.z * sC)[off] = f;
            }
        }
    }
}

// ---------------------------------------------------------------------------
// Row softmax over causal prefix, in place on bf16 scores; zero-fill (q,128b]
// ---------------------------------------------------------------------------
__launch_bounds__(256)
__global__ void softmax_rows(u16* __restrict__ sc)
{
    __shared__ float v[SEQ];
    __shared__ float red[8];
    const int bq = blockIdx.x;
    const int q  = bq & (SEQ - 1);
    u16* row = sc + (size_t)bq * SEQ;
    const int tid = threadIdx.x;
    const int nk = q + 1;
    const int bound = ((q >> 7) + 1) << 7;   // next multiple of 128

    float lmax = -1e30f;
    for (int k = tid; k < nk; k += 256) { float f = bf2f(row[k]); v[k] = f; lmax = fmaxf(lmax, f); }
    for (int off = 32; off; off >>= 1) lmax = fmaxf(lmax, __shfl_xor(lmax, off));
    if ((tid & 63) == 0) red[tid >> 6] = lmax;
    __syncthreads();
    const float m = fmaxf(fmaxf(red[0], red[1]), fmaxf(red[2], red[3]));

    float ls = 0.f;
    for (int k = tid; k < nk; k += 256) { float e = __expf(v[k] - m); v[k] = e; ls += e; }
    for (int off = 32; off; off >>= 1) ls += __shfl_xor(ls, off);
    if ((tid & 63) == 0) red[4 + (tid >> 6)] = ls;
    __syncthreads();
    const float inv = 1.f / (red[4] + red[5] + red[6] + red[7]);

    for (int k = tid; k < nk; k += 256)      row[k] = f2bf(v[k] * inv);
    for (int k = nk + tid; k < bound; k += 256) row[k] = 0;
}

// ---------------------------------------------------------------------------
// fp32 -> bf16 transpose (32x32 LDS tiles): out[c][r] = in[r][c]
// ---------------------------------------------------------------------------
__launch_bounds__(256)
__global__ void transpose_cvt(const float* __restrict__ in, u16* __restrict__ out,
                              int R, int Cc, long sIn, long sOut)
{
    __shared__ float t[32][33];
    in  += (long)blockIdx.z * sIn;
    out += (long)blockIdx.z * sOut;
    const int c0 = blockIdx.x * 32, r0 = blockIdx.y * 32;
    const int tx = threadIdx.x & 31, ty = threadIdx.x >> 5;   // ty 0..7
    #pragma unroll
    for (int i = 0; i < 32; i += 8) t[ty + i][tx] = in[(size_t)(r0 + ty + i) * Cc + c0 + tx];
    __syncthreads();
    #pragma unroll
    for (int i = 0; i < 32; i += 8) out[(size_t)(c0 + ty + i) * R + r0 + tx] = f2bf(t[tx][ty + i]);
}

// fp32 -> bf16 straight convert (vectorized), n4 = n/4
__launch_bounds__(256)
__global__ void convert_cvt(const float* __restrict__ in, u16* __restrict__ out, int n4)
{
    for (int i = blockIdx.x * 256 + threadIdx.x; i < n4; i += gridDim.x * 256) {
        float4 f = reinterpret_cast<const float4*>(in)[i];
        u16x4 o = { f2bf(f.x), f2bf(f.y), f2bf(f.z), f2bf(f.w) };
        reinterpret_cast<u16x4*>(out)[i] = o;
    }
}

// ---------------------------------------------------------------------------
extern "C" void kernel_launch(void* const* d_in, const int* in_sizes, int n_in,
                              void* d_out, int out_size, void* d_ws, size_t ws_size,
                              hipStream_t stream)
{
    const float* x    = (const float*)d_in[0];
    const float* A    = (const float*)d_in[1];
    const float* Bm   = (const float*)d_in[2];
    const float* ov   = (const float*)d_in[3];
    const float* mask = (const float*)d_in[4];

    // workspace layout (bf16): total ~86.5 MiB
    char* w = (char*)d_ws;
    u16* xb  = (u16*)w; w += (size_t)BS_ROWS * D_MODEL * 2;   // x row-major
    u16* xbT = (u16*)w; w += (size_t)BS_ROWS * D_MODEL * 2;   // x^T per batch [D][S]
    u16* AbT = (u16*)w; w += (size_t)C_DIM * D_MODEL * 2;     // A^T [C][D]
    u16* Bmb = (u16*)w; w += (size_t)C_DIM * D_MODEL * 2;     // Bmat [C][D]
    u16* ovT = (u16*)w; w += (size_t)D_MODEL * D_MODEL * 2;   // ov^T [D][D]
    u16* qm  = (u16*)w; w += (size_t)BS_ROWS * C_DIM * 2;     // masked q
    u16* kk  = (u16*)w; w += (size_t)BS_ROWS * C_DIM * 2;     // k
    u16* sc  = (u16*)w; w += (size_t)BATCH * SEQ * SEQ * 2;   // scores -> P (in place)
    u16* zb  = (u16*)w; w += (size_t)BS_ROWS * D_MODEL * 2;   // z

    // conversions / transposes
    convert_cvt<<<2048, 256, 0, stream>>>(x, xb, BS_ROWS * D_MODEL / 4);
    convert_cvt<<<128, 256, 0, stream>>>(Bm, Bmb, C_DIM * D_MODEL / 4);
    transpose_cvt<<<dim3(D_MODEL/32, SEQ/32, BATCH), 256, 0, stream>>>(
        x, xbT, SEQ, D_MODEL, (long)SEQ * D_MODEL, (long)D_MODEL * SEQ);
    transpose_cvt<<<dim3(D_MODEL/32, D_MODEL/32, 1), 256, 0, stream>>>(
        ov, ovT, D_MODEL, D_MODEL, 0, 0);
    transpose_cvt<<<dim3(C_DIM/32, D_MODEL/32, 1), 256, 0, stream>>>(
        A, AbT, D_MODEL, C_DIM, 0, 0);

    // q = (x@A)*mask, k = x@Bmat^T   (M=8192, N=128, K=1024)
    gemm_bt<1,1,0,0><<<dim3(BS_ROWS/128, 1, 1), 256, 0, stream>>>(
        xb, AbT, qm, mask, BS_ROWS, C_DIM, D_MODEL, D_MODEL, D_MODEL, C_DIM, 0, 0, 0, 1.0f);
    gemm_bt<1,0,0,0><<<dim3(BS_ROWS/128, 1, 1), 256, 0, stream>>>(
        xb, Bmb, kk, nullptr, BS_ROWS, C_DIM, D_MODEL, D_MODEL, D_MODEL, C_DIM, 0, 0, 0, 1.0f);

    // scores = qm @ kk^T / D  (per batch, causal lower tiles only)
    gemm_bt<1,0,1,0><<<dim3(SEQ/128, SEQ/128, BATCH), 256, 0, stream>>>(
        qm, kk, sc, nullptr, SEQ, SEQ, C_DIM, C_DIM, C_DIM, SEQ,
        (long)SEQ * C_DIM, (long)SEQ * C_DIM, (long)SEQ * SEQ, 1.0f / D_MODEL);

    softmax_rows<<<BS_ROWS, 256, 0, stream>>>(sc);

    // z = P @ x  (per batch, causal K-extent)
    gemm_bt<1,0,0,1><<<dim3(SEQ/128, D_MODEL/128, BATCH), 256, 0, stream>>>(
        sc, xbT, zb, nullptr, SEQ, D_MODEL, SEQ, SEQ, SEQ, D_MODEL,
        (long)SEQ * SEQ, (long)D_MODEL * SEQ, (long)SEQ * D_MODEL, 1.0f);

    // out = z @ ov  (M=8192, N=1024, K=1024), fp32 out
    gemm_bt<0,0,0,0><<<dim3(BS_ROWS/128, D_MODEL/128, 1), 256, 0, stream>>>(
        zb, ovT, d_out, nullptr, BS_ROWS, D_MODEL, D_MODEL, D_MODEL, D_MODEL, D_MODEL,
        0, 0, 0, 1.0f);
}

// Round 3
// 137.792 us; speedup vs baseline: 21.8866x; 1.1764x over previous
//
#include <hip/hip_runtime.h>
#include <hip/hip_bf16.h>
#include <math.h>

#define D_MODEL 1024
#define C_DIM   128
#define BATCH   4
#define SEQ     2048
#define BS_ROWS (BATCH*SEQ)

typedef float  f32x4 __attribute__((ext_vector_type(4)));
typedef short  s16x8 __attribute__((ext_vector_type(8)));
typedef unsigned short u16;
typedef unsigned short u16x4 __attribute__((ext_vector_type(4)));
typedef unsigned short u16x8 __attribute__((ext_vector_type(8)));

__device__ inline u16 f2bf(float f){
    unsigned u = __builtin_bit_cast(unsigned, f);
    u += 0x7FFF + ((u >> 16) & 1);          // round-to-nearest-even
    return (u16)(u >> 16);
}
__device__ inline float bf2f(u16 h){
    unsigned u = ((unsigned)h) << 16;
    return __builtin_bit_cast(float, u);
}

// async global->LDS, 16B per lane; LDS dest = wave-uniform base + lane*16
__device__ inline void gl_lds16(const u16* g, u16* l){
    __builtin_amdgcn_global_load_lds(
        (const __attribute__((address_space(1))) void*)g,
        (__attribute__((address_space(3))) void*)l,
        16, 0, 0);
}

// ---------------------------------------------------------------------------
// bf16 MFMA GEMM:  C[M,N] = scale * A[M,K] @ BT[N,K]^T
// 128x128 tile, BK=64, 4 waves, 4x4 frags of 16x16x32 MFMA.
// 2-phase double-buffered LDS pipeline (T3 minimum recipe).
// OUT_BF16: bf16 output. MASK: fp32 mask multiply in epilogue.
// CSKIP: skip tiles nt>mt (causal scores). CK: causal K-extent (mt+1)*128.
// QKF: fused q/k projection — blockIdx.y picks {Bg,Cg,mask} vs {Bg2,Cg2}.
// ---------------------------------------------------------------------------
template<int OUT_BF16, int MASK, int CSKIP, int CK, int QKF>
__launch_bounds__(256, 2)
__global__ void gemm_bt(const u16* __restrict__ Ag, const u16* __restrict__ Bg,
                        const u16* __restrict__ Bg2,
                        void* __restrict__ Cg, void* __restrict__ Cg2,
                        const float* __restrict__ maskp,
                        int M, int N, int K, int lda, int ldb, int ldc,
                        long sA, long sB, long sC, float scale)
{
    __shared__ u16 As[2][128*64];
    __shared__ u16 Bs[2][128*64];
    const int mt = blockIdx.x;
    const int nt = QKF ? 0 : blockIdx.y;
    if (CSKIP && nt > mt) return;
    const u16* Aa = Ag + (long)blockIdx.z * sA;
    const u16* Bsrc = (QKF && blockIdx.y) ? Bg2 : Bg;
    const u16* Bb = Bsrc + (long)blockIdx.z * sB;
    const int tid = threadIdx.x, lane = tid & 63, wave = tid >> 6;
    const int wr = wave >> 1, wc = wave & 1;
    const int mbase = mt * 128, nbase = nt * 128;
    int Keff = K;
    if (CK) { int ke = (mt + 1) * 128; Keff = ke < K ? ke : K; }
    const int nkt = Keff >> 6;

    f32x4 acc[4][4];
    #pragma unroll
    for (int m = 0; m < 4; ++m)
        #pragma unroll
        for (int n = 0; n < 4; ++n) acc[m][n] = (f32x4){0.f,0.f,0.f,0.f};

    // staging lane geometry: chunk = 8 rows x 64 cols (1KB); lane covers 16B
    const int sr  = lane >> 3;                 // row within chunk (0..7)
    const int sc8 = (lane & 7) ^ sr;           // XOR-swizzled 8-elem col slot

    auto STAGE = [&](int buf, int kt) {
        const int k0 = kt * 64;
        #pragma unroll
        for (int i = 0; i < 4; ++i) {
            const int chunk = wave * 4 + i;    // 0..15
            const int row = chunk * 8 + sr;
            gl_lds16(Aa + (size_t)(mbase + row) * lda + k0 + sc8 * 8, &As[buf][chunk * 512]);
            gl_lds16(Bb + (size_t)(nbase + row) * ldb + k0 + sc8 * 8, &Bs[buf][chunk * 512]);
        }
    };

    STAGE(0, 0);
    asm volatile("s_waitcnt vmcnt(0)" ::: "memory");
    __syncthreads();

    int cur = 0;
    for (int kt = 0; kt < nkt; ++kt) {
        if (kt + 1 < nkt) STAGE(cur ^ 1, kt + 1);   // prefetch next tile

        const u16* Ap = As[cur];
        const u16* Bp = Bs[cur];
        #pragma unroll
        for (int ks = 0; ks < 2; ++ks) {
            s16x8 af[4], bfr[4];
            const int k8 = ks * 4 + (lane >> 4);
            #pragma unroll
            for (int m = 0; m < 4; ++m) {
                const int row = wr * 64 + m * 16 + (lane & 15);
                af[m] = *(const s16x8*)&Ap[row * 64 + ((k8 ^ (row & 7)) << 3)];
            }
            #pragma unroll
            for (int n = 0; n < 4; ++n) {
                const int row = wc * 64 + n * 16 + (lane & 15);
                bfr[n] = *(const s16x8*)&Bp[row * 64 + ((k8 ^ (row & 7)) << 3)];
            }
            #pragma unroll
            for (int m = 0; m < 4; ++m)
                #pragma unroll
                for (int n = 0; n < 4; ++n)
                    acc[m][n] = __builtin_amdgcn_mfma_f32_16x16x32_bf16(af[m], bfr[n], acc[m][n], 0, 0, 0);
        }
        asm volatile("s_waitcnt vmcnt(0)" ::: "memory");
        __syncthreads();
        cur ^= 1;
    }

    // epilogue: C/D layout col=lane&15, row=(lane>>4)*4+r (m89-verified)
    const bool kpath = QKF && blockIdx.y;
    void* Cout = kpath ? Cg2 : Cg;
    const int lr = (lane >> 4) * 4, lc = lane & 15;
    #pragma unroll
    for (int m = 0; m < 4; ++m) {
        #pragma unroll
        for (int n = 0; n < 4; ++n) {
            const int gr = mbase + wr * 64 + m * 16 + lr;
            const int gc = nbase + wc * 64 + n * 16 + lc;
            #pragma unroll
            for (int r = 0; r < 4; ++r) {
                float f = acc[m][n][r] * scale;
                const size_t off = (size_t)(gr + r) * ldc + gc;
                if (MASK) { if (!kpath) f *= maskp[(long)blockIdx.z * sC + off]; }
                if (OUT_BF16) ((u16*)Cout + (long)blockIdx.z * sC)[off] = f2bf(f);
                else          ((float*)Cout + (long)blockIdx.z * sC)[off] = f;
            }
        }
    }
}

// ---------------------------------------------------------------------------
// Row softmax over causal prefix, in place on bf16 scores (vectorized).
// Masked lanes fold to exp->0, which also zero-fills (q, bound).
// ---------------------------------------------------------------------------
__launch_bounds__(256)
__global__ void softmax_rows(u16* __restrict__ sc)
{
    __shared__ float v[SEQ];
    __shared__ float red[8];
    const int bq = blockIdx.x;
    const int q  = bq & (SEQ - 1);
    u16* row = sc + (size_t)bq * SEQ;
    const int tid = threadIdx.x;
    const int nk = q + 1;
    const int bound = ((q >> 7) + 1) << 7;   // next multiple of 128
    const int nv = bound >> 3;               // u16x8 chunks

    float lmax = -1e30f;
    for (int ci = tid; ci < nv; ci += 256) {
        const int base = ci * 8;
        u16x8 vv = *(const u16x8*)&row[base];
        #pragma unroll
        for (int j = 0; j < 8; ++j) {
            float f = (base + j < nk) ? bf2f(vv[j]) : -1e30f;
            v[base + j] = f;
            lmax = fmaxf(lmax, f);
        }
    }
    for (int off = 32; off; off >>= 1) lmax = fmaxf(lmax, __shfl_xor(lmax, off));
    if ((tid & 63) == 0) red[tid >> 6] = lmax;
    __syncthreads();
    const float m = fmaxf(fmaxf(red[0], red[1]), fmaxf(red[2], red[3]));

    float ls = 0.f;
    for (int ci = tid; ci < nv; ci += 256) {
        const int base = ci * 8;
        #pragma unroll
        for (int j = 0; j < 8; ++j) {
            float e = __expf(v[base + j] - m);   // masked: exp(-1e30-m)=0
            v[base + j] = e;
            ls += e;
        }
    }
    for (int off = 32; off; off >>= 1) ls += __shfl_xor(ls, off);
    if ((tid & 63) == 0) red[4 + (tid >> 6)] = ls;
    __syncthreads();
    const float inv = 1.f / (red[4] + red[5] + red[6] + red[7]);

    for (int ci = tid; ci < nv; ci += 256) {
        const int base = ci * 8;
        u16x8 o;
        #pragma unroll
        for (int j = 0; j < 8; ++j) o[j] = f2bf(v[base + j] * inv);
        *(u16x8*)&row[base] = o;
    }
}

// ---------------------------------------------------------------------------
// x prep: read x once; write xb (bf16 row-major) and xbT (bf16 [b][D][S])
// ---------------------------------------------------------------------------
__launch_bounds__(256)
__global__ void xprep(const float* __restrict__ x, u16* __restrict__ xb,
                      u16* __restrict__ xbT)
{
    __shared__ float t[32][33];
    const int b = blockIdx.z;
    const float* xp = x + (long)b * SEQ * D_MODEL;
    const int c0 = blockIdx.x * 32, r0 = blockIdx.y * 32;
    const int tx = threadIdx.x & 31, ty = threadIdx.x >> 5;   // ty 0..7
    #pragma unroll
    for (int i = 0; i < 32; i += 8) {
        const float f = xp[(size_t)(r0 + ty + i) * D_MODEL + c0 + tx];
        t[ty + i][tx] = f;
        xb[((long)b * SEQ + r0 + ty + i) * D_MODEL + c0 + tx] = f2bf(f);
    }
    __syncthreads();
    #pragma unroll
    for (int i = 0; i < 32; i += 8)
        xbT[((long)b * D_MODEL + c0 + ty + i) * SEQ + r0 + tx] = f2bf(t[tx][ty + i]);
}

// ---------------------------------------------------------------------------
// fp32 -> bf16 transpose (32x32 LDS tiles): out[c][r] = in[r][c]
// ---------------------------------------------------------------------------
__launch_bounds__(256)
__global__ void transpose_cvt(const float* __restrict__ in, u16* __restrict__ out,
                              int R, int Cc)
{
    __shared__ float t[32][33];
    const int c0 = blockIdx.x * 32, r0 = blockIdx.y * 32;
    const int tx = threadIdx.x & 31, ty = threadIdx.x >> 5;
    #pragma unroll
    for (int i = 0; i < 32; i += 8) t[ty + i][tx] = in[(size_t)(r0 + ty + i) * Cc + c0 + tx];
    __syncthreads();
    #pragma unroll
    for (int i = 0; i < 32; i += 8) out[(size_t)(c0 + ty + i) * R + r0 + tx] = f2bf(t[tx][ty + i]);
}

// fp32 -> bf16 straight convert (vectorized), n4 = n/4
__launch_bounds__(256)
__global__ void convert_cvt(const float* __restrict__ in, u16* __restrict__ out, int n4)
{
    for (int i = blockIdx.x * 256 + threadIdx.x; i < n4; i += gridDim.x * 256) {
        float4 f = reinterpret_cast<const float4*>(in)[i];
        u16x4 o = { f2bf(f.x), f2bf(f.y), f2bf(f.z), f2bf(f.w) };
        reinterpret_cast<u16x4*>(out)[i] = o;
    }
}

// ---------------------------------------------------------------------------
extern "C" void kernel_launch(void* const* d_in, const int* in_sizes, int n_in,
                              void* d_out, int out_size, void* d_ws, size_t ws_size,
                              hipStream_t stream)
{
    const float* x    = (const float*)d_in[0];
    const float* A    = (const float*)d_in[1];
    const float* Bm   = (const float*)d_in[2];
    const float* ov   = (const float*)d_in[3];
    const float* mask = (const float*)d_in[4];

    // workspace layout (bf16): total ~86.5 MiB
    char* w = (char*)d_ws;
    u16* xb  = (u16*)w; w += (size_t)BS_ROWS * D_MODEL * 2;   // x row-major
    u16* xbT = (u16*)w; w += (size_t)BS_ROWS * D_MODEL * 2;   // x^T per batch [D][S]
    u16* AbT = (u16*)w; w += (size_t)C_DIM * D_MODEL * 2;     // A^T [C][D]
    u16* Bmb = (u16*)w; w += (size_t)C_DIM * D_MODEL * 2;     // Bmat [C][D]
    u16* ovT = (u16*)w; w += (size_t)D_MODEL * D_MODEL * 2;   // ov^T [D][D]
    u16* qm  = (u16*)w; w += (size_t)BS_ROWS * C_DIM * 2;     // masked q
    u16* kk  = (u16*)w; w += (size_t)BS_ROWS * C_DIM * 2;     // k
    u16* sc  = (u16*)w; w += (size_t)BATCH * SEQ * SEQ * 2;   // scores -> P (in place)
    u16* zb  = (u16*)w; w += (size_t)BS_ROWS * D_MODEL * 2;   // z

    // prep: x (read once -> xb + xbT), Bmat convert, ov/A transposes
    xprep<<<dim3(D_MODEL/32, SEQ/32, BATCH), 256, 0, stream>>>(x, xb, xbT);
    convert_cvt<<<128, 256, 0, stream>>>(Bm, Bmb, C_DIM * D_MODEL / 4);
    transpose_cvt<<<dim3(D_MODEL/32, D_MODEL/32, 1), 256, 0, stream>>>(ov, ovT, D_MODEL, D_MODEL);
    transpose_cvt<<<dim3(C_DIM/32, D_MODEL/32, 1), 256, 0, stream>>>(A, AbT, D_MODEL, C_DIM);

    // fused q & k projection: y=0 -> qm=(x@A)*mask, y=1 -> kk=x@Bmat^T
    gemm_bt<1,1,0,0,1><<<dim3(BS_ROWS/128, 2, 1), 256, 0, stream>>>(
        xb, AbT, Bmb, qm, kk, mask,
        BS_ROWS, C_DIM, D_MODEL, D_MODEL, D_MODEL, C_DIM, 0, 0, 0, 1.0f);

    // scores = qm @ kk^T / D  (per batch, causal lower tiles only)
    gemm_bt<1,0,1,0,0><<<dim3(SEQ/128, SEQ/128, BATCH), 256, 0, stream>>>(
        qm, kk, nullptr, sc, nullptr, nullptr, SEQ, SEQ, C_DIM, C_DIM, C_DIM, SEQ,
        (long)SEQ * C_DIM, (long)SEQ * C_DIM, (long)SEQ * SEQ, 1.0f / D_MODEL);

    softmax_rows<<<BS_ROWS, 256, 0, stream>>>(sc);

    // z = P @ x  (per batch, causal K-extent)
    gemm_bt<1,0,0,1,0><<<dim3(SEQ/128, D_MODEL/128, BATCH), 256, 0, stream>>>(
        sc, xbT, nullptr, zb, nullptr, nullptr, SEQ, D_MODEL, SEQ, SEQ, SEQ, D_MODEL,
        (long)SEQ * SEQ, (long)D_MODEL * SEQ, (long)SEQ * D_MODEL, 1.0f);

    // out = z @ ov  (M=8192, N=1024, K=1024), fp32 out
    gemm_bt<0,0,0,0,0><<<dim3(BS_ROWS/128, D_MODEL/128, 1), 256, 0, stream>>>(
        zb, ovT, nullptr, d_out, nullptr, nullptr, BS_ROWS, D_MODEL, D_MODEL, D_MODEL, D_MODEL, D_MODEL,
        0, 0, 0, 1.0f);
}

// Round 4
// 123.199 us; speedup vs baseline: 24.4791x; 1.1185x over previous
//
#include <hip/hip_runtime.h>
#include <hip/hip_bf16.h>
#include <math.h>

#define D_MODEL 1024
#define C_DIM   128
#define BATCH   4
#define SEQ     2048
#define BS_ROWS (BATCH*SEQ)

typedef float  f32x4 __attribute__((ext_vector_type(4)));
typedef short  s16x8 __attribute__((ext_vector_type(8)));
typedef unsigned short u16;
typedef unsigned short u16x4 __attribute__((ext_vector_type(4)));
typedef unsigned short u16x8 __attribute__((ext_vector_type(8)));

__device__ inline u16 f2bf(float f){
    unsigned u = __builtin_bit_cast(unsigned, f);
    u += 0x7FFF + ((u >> 16) & 1);          // round-to-nearest-even
    return (u16)(u >> 16);
}
__device__ inline float bf2f(u16 h){
    unsigned u = ((unsigned)h) << 16;
    return __builtin_bit_cast(float, u);
}

// async global->LDS, 16B per lane; LDS dest = wave-uniform base + lane*16
__device__ inline void gl_lds16(const u16* g, u16* l){
    __builtin_amdgcn_global_load_lds(
        (const __attribute__((address_space(1))) void*)g,
        (__attribute__((address_space(3))) void*)l,
        16, 0, 0);
}

// ---------------------------------------------------------------------------
// bf16 MFMA GEMM:  C[M,N] = scale * A[M,K] @ BT[N,K]^T
// BMxBN tile, BK=64, 4 waves in 2x2 grid, per-wave (BM/2)x(BN/2) via
// FM x FN frags of 16x16x32 MFMA. m97 structure: single-buffer LDS,
// stage -> vmcnt(0)+barrier -> compute -> barrier; TLP (4+ blocks/CU)
// provides the pipelining.
// OUT_BF16: bf16 output. MASK: fp32 mask multiply in epilogue (q path only).
// CSKIP: skip tiles fully above causal diagonal. CK: causal K-extent.
// QKF: fused q/k projection — blockIdx.y = path*(128/BN)+nt.
// ---------------------------------------------------------------------------
template<int BM, int BN, int OUT_BF16, int MASK, int CSKIP, int CK, int QKF>
__launch_bounds__(256)
__global__ void gemm_bt(const u16* __restrict__ Ag, const u16* __restrict__ Bg,
                        const u16* __restrict__ Bg2,
                        void* __restrict__ Cg, void* __restrict__ Cg2,
                        const float* __restrict__ maskp,
                        int K, int lda, int ldb, int ldc,
                        long sA, long sB, long sC, float scale)
{
    constexpr int FM = BM / 32, FN = BN / 32;
    __shared__ u16 As[BM * 64];
    __shared__ u16 Bs[BN * 64];
    const int mt = blockIdx.x;
    int nt, path = 0;
    if (QKF) { constexpr int NT = C_DIM / BN; path = blockIdx.y / NT; nt = blockIdx.y % NT; }
    else nt = blockIdx.y;
    if (CSKIP && nt * BN >= (mt + 1) * BM) return;   // fully above diagonal
    const u16* Aa = Ag + (long)blockIdx.z * sA;
    const u16* Bb = ((QKF && path) ? Bg2 : Bg) + (long)blockIdx.z * sB;
    const int tid = threadIdx.x, lane = tid & 63, wave = tid >> 6;
    const int wr = wave >> 1, wc = wave & 1;
    const int mbase = mt * BM, nbase = nt * BN;
    int Keff = K;
    if (CK) { int ke = (mt + 1) * BM; Keff = ke < K ? ke : K; }
    const int nkt = Keff >> 6;

    f32x4 acc[FM][FN];
    #pragma unroll
    for (int m = 0; m < FM; ++m)
        #pragma unroll
        for (int n = 0; n < FN; ++n) acc[m][n] = (f32x4){0.f,0.f,0.f,0.f};

    // staging lane geometry: each wave stages 8 rows x 128B per shot;
    // lane covers 16B at XOR-swizzled col slot
    const int sr  = lane >> 3;                 // row within wave-chunk (0..7)
    const int sc8 = (lane & 7) ^ sr;           // swizzled 8-elem col slot

    for (int kt = 0; kt < nkt; ++kt) {
        const int k0 = kt * 64;
        #pragma unroll
        for (int s = 0; s < BM / 32; ++s) {
            const int row = s * 32 + wave * 8 + sr;
            gl_lds16(Aa + (size_t)(mbase + row) * lda + k0 + sc8 * 8,
                     &As[s * 2048 + wave * 512]);
        }
        #pragma unroll
        for (int s = 0; s < BN / 32; ++s) {
            const int row = s * 32 + wave * 8 + sr;
            gl_lds16(Bb + (size_t)(nbase + row) * ldb + k0 + sc8 * 8,
                     &Bs[s * 2048 + wave * 512]);
        }
        asm volatile("s_waitcnt vmcnt(0)" ::: "memory");
        __syncthreads();

        #pragma unroll
        for (int ks = 0; ks < 2; ++ks) {
            s16x8 af[FM], bfr[FN];
            const int k8 = ks * 4 + (lane >> 4);
            #pragma unroll
            for (int m = 0; m < FM; ++m) {
                const int row = wr * (BM / 2) + m * 16 + (lane & 15);
                af[m] = *(const s16x8*)&As[row * 64 + ((k8 ^ (row & 7)) << 3)];
            }
            #pragma unroll
            for (int n = 0; n < FN; ++n) {
                const int row = wc * (BN / 2) + n * 16 + (lane & 15);
                bfr[n] = *(const s16x8*)&Bs[row * 64 + ((k8 ^ (row & 7)) << 3)];
            }
            #pragma unroll
            for (int m = 0; m < FM; ++m)
                #pragma unroll
                for (int n = 0; n < FN; ++n)
                    acc[m][n] = __builtin_amdgcn_mfma_f32_16x16x32_bf16(af[m], bfr[n], acc[m][n], 0, 0, 0);
        }
        __syncthreads();
    }

    // epilogue: C/D layout col=lane&15, row=(lane>>4)*4+r (m89-verified)
    const bool kpath = QKF && path;
    void* Cout = kpath ? Cg2 : Cg;
    const int lr = (lane >> 4) * 4, lc = lane & 15;
    #pragma unroll
    for (int m = 0; m < FM; ++m) {
        #pragma unroll
        for (int n = 0; n < FN; ++n) {
            const int gr = mbase + wr * (BM / 2) + m * 16 + lr;
            const int gc = nbase + wc * (BN / 2) + n * 16 + lc;
            #pragma unroll
            for (int r = 0; r < 4; ++r) {
                float f = acc[m][n][r] * scale;
                const size_t off = (size_t)(gr + r) * ldc + gc;
                if (MASK) { if (!kpath) f *= maskp[(long)blockIdx.z * sC + off]; }
                if (OUT_BF16) ((u16*)Cout + (long)blockIdx.z * sC)[off] = f2bf(f);
                else          ((float*)Cout + (long)blockIdx.z * sC)[off] = f;
            }
        }
    }
}

// ---------------------------------------------------------------------------
// Row softmax over causal prefix, in place on bf16 scores (vectorized).
// Masked lanes fold to exp->0, which also zero-fills (q, 128-boundary).
// ---------------------------------------------------------------------------
__launch_bounds__(256)
__global__ void softmax_rows(u16* __restrict__ sc)
{
    __shared__ float v[SEQ];
    __shared__ float red[8];
    const int bq = blockIdx.x;
    const int q  = bq & (SEQ - 1);
    u16* row = sc + (size_t)bq * SEQ;
    const int tid = threadIdx.x;
    const int nk = q + 1;
    const int bound = ((q >> 7) + 1) << 7;   // next multiple of 128
    const int nv = bound >> 3;               // u16x8 chunks

    float lmax = -1e30f;
    for (int ci = tid; ci < nv; ci += 256) {
        const int base = ci * 8;
        u16x8 vv = *(const u16x8*)&row[base];
        #pragma unroll
        for (int j = 0; j < 8; ++j) {
            float f = (base + j < nk) ? bf2f(vv[j]) : -1e30f;
            v[base + j] = f;
            lmax = fmaxf(lmax, f);
        }
    }
    for (int off = 32; off; off >>= 1) lmax = fmaxf(lmax, __shfl_xor(lmax, off));
    if ((tid & 63) == 0) red[tid >> 6] = lmax;
    __syncthreads();
    const float m = fmaxf(fmaxf(red[0], red[1]), fmaxf(red[2], red[3]));

    float ls = 0.f;
    for (int ci = tid; ci < nv; ci += 256) {
        const int base = ci * 8;
        #pragma unroll
        for (int j = 0; j < 8; ++j) {
            float e = __expf(v[base + j] - m);   // masked: exp(-1e30-m)=0
            v[base + j] = e;
            ls += e;
        }
    }
    for (int off = 32; off; off >>= 1) ls += __shfl_xor(ls, off);
    if ((tid & 63) == 0) red[4 + (tid >> 6)] = ls;
    __syncthreads();
    const float inv = 1.f / (red[4] + red[5] + red[6] + red[7]);

    for (int ci = tid; ci < nv; ci += 256) {
        const int base = ci * 8;
        u16x8 o;
        #pragma unroll
        for (int j = 0; j < 8; ++j) o[j] = f2bf(v[base + j] * inv);
        *(u16x8*)&row[base] = o;
    }
}

// ---------------------------------------------------------------------------
// x prep: read x once; write xb (bf16 row-major) and xbT (bf16 [b][D][S])
// ---------------------------------------------------------------------------
__launch_bounds__(256)
__global__ void xprep(const float* __restrict__ x, u16* __restrict__ xb,
                      u16* __restrict__ xbT)
{
    __shared__ float t[32][33];
    const int b = blockIdx.z;
    const float* xp = x + (long)b * SEQ * D_MODEL;
    const int c0 = blockIdx.x * 32, r0 = blockIdx.y * 32;
    const int tx = threadIdx.x & 31, ty = threadIdx.x >> 5;   // ty 0..7
    #pragma unroll
    for (int i = 0; i < 32; i += 8) {
        const float f = xp[(size_t)(r0 + ty + i) * D_MODEL + c0 + tx];
        t[ty + i][tx] = f;
        xb[((long)b * SEQ + r0 + ty + i) * D_MODEL + c0 + tx] = f2bf(f);
    }
    __syncthreads();
    #pragma unroll
    for (int i = 0; i < 32; i += 8)
        xbT[((long)b * D_MODEL + c0 + ty + i) * SEQ + r0 + tx] = f2bf(t[tx][ty + i]);
}

// ---------------------------------------------------------------------------
// fp32 -> bf16 transpose (32x32 LDS tiles): out[c][r] = in[r][c]
// ---------------------------------------------------------------------------
__launch_bounds__(256)
__global__ void transpose_cvt(const float* __restrict__ in, u16* __restrict__ out,
                              int R, int Cc)
{
    __shared__ float t[32][33];
    const int c0 = blockIdx.x * 32, r0 = blockIdx.y * 32;
    const int tx = threadIdx.x & 31, ty = threadIdx.x >> 5;
    #pragma unroll
    for (int i = 0; i < 32; i += 8) t[ty + i][tx] = in[(size_t)(r0 + ty + i) * Cc + c0 + tx];
    __syncthreads();
    #pragma unroll
    for (int i = 0; i < 32; i += 8) out[(size_t)(c0 + ty + i) * R + r0 + tx] = f2bf(t[tx][ty + i]);
}

// fp32 -> bf16 straight convert (vectorized), n4 = n/4
__launch_bounds__(256)
__global__ void convert_cvt(const float* __restrict__ in, u16* __restrict__ out, int n4)
{
    for (int i = blockIdx.x * 256 + threadIdx.x; i < n4; i += gridDim.x * 256) {
        float4 f = reinterpret_cast<const float4*>(in)[i];
        u16x4 o = { f2bf(f.x), f2bf(f.y), f2bf(f.z), f2bf(f.w) };
        reinterpret_cast<u16x4*>(out)[i] = o;
    }
}

// ---------------------------------------------------------------------------
extern "C" void kernel_launch(void* const* d_in, const int* in_sizes, int n_in,
                              void* d_out, int out_size, void* d_ws, size_t ws_size,
                              hipStream_t stream)
{
    const float* x    = (const float*)d_in[0];
    const float* A    = (const float*)d_in[1];
    const float* Bm   = (const float*)d_in[2];
    const float* ov   = (const float*)d_in[3];
    const float* mask = (const float*)d_in[4];

    // workspace layout (bf16): total ~86.5 MiB
    char* w = (char*)d_ws;
    u16* xb  = (u16*)w; w += (size_t)BS_ROWS * D_MODEL * 2;   // x row-major
    u16* xbT = (u16*)w; w += (size_t)BS_ROWS * D_MODEL * 2;   // x^T per batch [D][S]
    u16* AbT = (u16*)w; w += (size_t)C_DIM * D_MODEL * 2;     // A^T [C][D]
    u16* Bmb = (u16*)w; w += (size_t)C_DIM * D_MODEL * 2;     // Bmat [C][D]
    u16* ovT = (u16*)w; w += (size_t)D_MODEL * D_MODEL * 2;   // ov^T [D][D]
    u16* qm  = (u16*)w; w += (size_t)BS_ROWS * C_DIM * 2;     // masked q
    u16* kk  = (u16*)w; w += (size_t)BS_ROWS * C_DIM * 2;     // k
    u16* sc  = (u16*)w; w += (size_t)BATCH * SEQ * SEQ * 2;   // scores -> P (in place)
    u16* zb  = (u16*)w; w += (size_t)BS_ROWS * D_MODEL * 2;   // z

    // prep: x (read once -> xb + xbT), Bmat convert, ov/A transposes
    xprep<<<dim3(D_MODEL/32, SEQ/32, BATCH), 256, 0, stream>>>(x, xb, xbT);
    convert_cvt<<<128, 256, 0, stream>>>(Bm, Bmb, C_DIM * D_MODEL / 4);
    transpose_cvt<<<dim3(D_MODEL/32, D_MODEL/32, 1), 256, 0, stream>>>(ov, ovT, D_MODEL, D_MODEL);
    transpose_cvt<<<dim3(C_DIM/32, D_MODEL/32, 1), 256, 0, stream>>>(A, AbT, D_MODEL, C_DIM);

    // fused q & k projection: 64x64 tiles, y = path*2 + nt -> 512 blocks
    gemm_bt<64,64,1,1,0,0,1><<<dim3(BS_ROWS/64, 4, 1), 256, 0, stream>>>(
        xb, AbT, Bmb, qm, kk, mask,
        D_MODEL, D_MODEL, D_MODEL, C_DIM, 0, 0, 0, 1.0f);

    // scores = qm @ kk^T / D  (128x64 tiles, causal lower tiles only)
    gemm_bt<128,64,1,0,1,0,0><<<dim3(SEQ/128, SEQ/64, BATCH), 256, 0, stream>>>(
        qm, kk, nullptr, sc, nullptr, nullptr, C_DIM, C_DIM, C_DIM, SEQ,
        (long)SEQ * C_DIM, (long)SEQ * C_DIM, (long)SEQ * SEQ, 1.0f / D_MODEL);

    softmax_rows<<<BS_ROWS, 256, 0, stream>>>(sc);

    // z = P @ x  (128x64 tiles, causal K-extent) -> 1024 blocks
    gemm_bt<128,64,1,0,0,1,0><<<dim3(SEQ/128, D_MODEL/64, BATCH), 256, 0, stream>>>(
        sc, xbT, nullptr, zb, nullptr, nullptr, SEQ, SEQ, SEQ, D_MODEL,
        (long)SEQ * SEQ, (long)D_MODEL * SEQ, (long)SEQ * D_MODEL, 1.0f);

    // out = z @ ov  (128x64 tiles) -> 1024 blocks, fp32 out
    gemm_bt<128,64,0,0,0,0,0><<<dim3(BS_ROWS/128, D_MODEL/64, 1), 256, 0, stream>>>(
        zb, ovT, nullptr, d_out, nullptr, nullptr, D_MODEL, D_MODEL, D_MODEL, D_MODEL,
        0, 0, 0, 1.0f);
}